// Round 7
// baseline (411.628 us; speedup 1.0000x reference)
//
#include <hip/hip_runtime.h>
#include <hip/hip_bf16.h>
#include <stdint.h>

// B=128, T=256, C=768, D=768. M_total = 32768.

typedef __attribute__((ext_vector_type(8))) short short8;   // 8 x bf16 (4 VGPRs)
typedef __attribute__((ext_vector_type(4))) short short4v;  // 4 x bf16 (8B)
typedef __attribute__((ext_vector_type(4))) float f32x4;

__device__ __forceinline__ short f2bf(float f) {
    uint32_t u = __float_as_uint(f);
    u += 0x7fffu + ((u >> 16) & 1u);   // RNE
    return (short)(u >> 16);
}

// ---------------------------------------------------------------------------
__global__ __launch_bounds__(256) void cvt_x(const float* __restrict__ x,
                                             short* __restrict__ xb) {
    long i = ((long)blockIdx.x * 256 + threadIdx.x) * 4;
    f32x4 v = *(const f32x4*)(x + i);
    short4v o;
    o.x = f2bf(v.x); o.y = f2bf(v.y); o.z = f2bf(v.z); o.w = f2bf(v.w);
    *(short4v*)(xb + i) = o;
}

// W [768,768] fp32 -> Wt [768,768] bf16 transposed
__global__ __launch_bounds__(256) void cvt_wt(const float* __restrict__ W,
                                              short* __restrict__ Wt) {
    __shared__ float tile[32][33];
    int d0 = blockIdx.x * 32, c0 = blockIdx.y * 32;
    int tr = threadIdx.x >> 5, tc = threadIdx.x & 31;
    #pragma unroll
    for (int i = 0; i < 32; i += 8)
        tile[tr + i][tc] = W[(long)(c0 + tr + i) * 768 + d0 + tc];
    __syncthreads();
    #pragma unroll
    for (int i = 0; i < 32; i += 8)
        Wt[(long)(d0 + tr + i) * 768 + c0 + tc] = f2bf(tile[tc][tr + i]);
}

// RoPE table: rt[t*384 + j] = (cos, sin)
__global__ __launch_bounds__(256) void rope_tab(float2* __restrict__ rt) {
    int i = blockIdx.x * 256 + threadIdx.x;   // 98304
    int t = i / 384, j = i - t * 384;
    const float CE = -0.034603417655f;        // -2*log2(10000)/768
    float th = exp2f((float)j * CE);
    float s, c;
    sincosf((float)t * th, &s, &c);
    rt[i] = make_float2(c, s);
}

// ---------------------------------------------------------------------------
// Fused QKV GEMM: 256x256 tile, BK=64, 8 waves (2Mx4N), 8-phase schedule with
// counted vmcnt (T3+T4), setprio around MFMA clusters (T5), rotation LDS
// swizzle (0 bank conflicts).
// C = A[32768x768] x B[2304x768]^T; epilogue: RoPE (q,k), transpose (v).
__global__ __launch_bounds__(512, 2)
void qkv256(const short* __restrict__ A, const short* __restrict__ B,
            short* __restrict__ Q, short* __restrict__ Kb,
            short* __restrict__ Vt, const float2* __restrict__ rt) {
    // grid 1152 flat = 8 XCDs x 16 M-stripes x 9 N-blocks (bijective)
    int p = blockIdx.x;
    int c = p & 7, j = p >> 3;          // j in [0,144)
    int st = j / 9;
    int bx = j - st * 9;                // [0,9)
    int by = c * 16 + st;               // [0,128)
    const int m0 = by * 256, n0 = bx * 256;

    __shared__ short lA[2][256 * 64];   // 64 KB
    __shared__ short lB[2][256 * 64];   // 64 KB

    const int tid = threadIdx.x;
    const int w = tid >> 6, lane = tid & 63;
    const int wm = (w >> 2) * 128;      // 2 M-waves
    const int wn = (w & 3) * 64;        // 4 N-waves
    const int lr8 = lane >> 3;
    const int scol = (((lane & 7) - lr8) & 7) * 8;  // rotation swizzle (stage)
    const int fr = lane & 15, kq = lane >> 4;

    f32x4 acc[8][4] = {};
    short8 af[4][2];
    short8 bq[4][2];

#define STAGE_HALF(lX, gX, r0g, h, t) do {                                     \
    int _buf = (t) & 1;                                                        \
    _Pragma("unroll")                                                          \
    for (int _i = 0; _i < 2; ++_i) {                                           \
        int _rl = (h) * 128 + (w * 2 + _i) * 8;                                \
        const short* _g = (gX) + (long)((r0g) + _rl + lr8) * 768               \
                               + (t) * 64 + scol;                              \
        __builtin_amdgcn_global_load_lds(                                      \
            (const __attribute__((address_space(1))) void*)_g,                 \
            (__attribute__((address_space(3))) void*)(&lX[_buf][_rl * 64]),    \
            16, 0, 0);                                                         \
    }                                                                          \
} while (0)

#define LOAD_A(mh, buf) do {                                                   \
    _Pragma("unroll")                                                          \
    for (int _t = 0; _t < 4; ++_t)                                             \
        _Pragma("unroll")                                                      \
        for (int _k = 0; _k < 2; ++_k)                                         \
            af[_t][_k] = *(const short8*)(&lA[buf][                            \
                (wm + (mh) * 64 + _t * 16 + fr) * 64 +                         \
                ((_k * 4 + kq + fr) & 7) * 8]);                                \
} while (0)

#define LOAD_B(nh, buf) do {                                                   \
    _Pragma("unroll")                                                          \
    for (int _t = 0; _t < 2; ++_t)                                             \
        _Pragma("unroll")                                                      \
        for (int _k = 0; _k < 2; ++_k)                                         \
            bq[(nh) * 2 + _t][_k] = *(const short8*)(&lB[buf][                 \
                (wn + (nh) * 32 + _t * 16 + fr) * 64 +                         \
                ((_k * 4 + kq + fr) & 7) * 8]);                                \
} while (0)

#define MMA_Q(mh, nh) do {                                                     \
    __builtin_amdgcn_s_setprio(1);                                             \
    _Pragma("unroll")                                                          \
    for (int _t = 0; _t < 4; ++_t)                                             \
        _Pragma("unroll")                                                      \
        for (int _n = 0; _n < 2; ++_n)                                         \
            _Pragma("unroll")                                                  \
            for (int _k = 0; _k < 2; ++_k)                                     \
                acc[(mh) * 4 + _t][(nh) * 2 + _n] =                            \
                    __builtin_amdgcn_mfma_f32_16x16x32_bf16(                   \
                        af[_t][_k], bq[(nh) * 2 + _n][_k],                     \
                        acc[(mh) * 4 + _t][(nh) * 2 + _n], 0, 0, 0);           \
    __builtin_amdgcn_s_setprio(0);                                             \
} while (0)

#define BAR() __builtin_amdgcn_s_barrier()
#define LGKM0() asm volatile("s_waitcnt lgkmcnt(0)" ::: "memory")
#define VMC4() asm volatile("s_waitcnt vmcnt(4)" ::: "memory")
#define VMC0() asm volatile("s_waitcnt vmcnt(0)" ::: "memory")

    // prologue: T0 {B0,B1,A0,A1}, T1 {B0,B1}; confirm T0
    STAGE_HALF(lB, B, n0, 0, 0);
    STAGE_HALF(lB, B, n0, 1, 0);
    STAGE_HALF(lA, A, m0, 0, 0);
    STAGE_HALF(lA, A, m0, 1, 0);
    STAGE_HALF(lB, B, n0, 0, 1);
    STAGE_HALF(lB, B, n0, 1, 1);
    VMC4();
    BAR();

    #pragma unroll 1
    for (int i = 0; i < 6; ++i) {
        const int t0 = 2 * i;
        const bool more = (i < 5);
        // phase 1
        LOAD_A(0, 0); LOAD_B(0, 0);
        STAGE_HALF(lA, A, m0, 0, t0 + 1);
        BAR(); LGKM0(); MMA_Q(0, 0); BAR();
        // phase 2
        LOAD_B(1, 0);
        STAGE_HALF(lA, A, m0, 1, t0 + 1);
        BAR(); LGKM0(); MMA_Q(0, 1); BAR();
        // phase 3
        LOAD_A(1, 0);
        if (more) STAGE_HALF(lB, B, n0, 0, t0 + 2);
        BAR(); LGKM0(); MMA_Q(1, 1); BAR();
        // phase 4: held regs; confirm tile 2i+1 after MFMA
        if (more) STAGE_HALF(lB, B, n0, 1, t0 + 2);
        BAR(); LGKM0(); MMA_Q(1, 0);
        if (more) { VMC4(); } else { VMC0(); }
        BAR();
        // phase 5
        LOAD_A(0, 1); LOAD_B(0, 1);
        if (more) STAGE_HALF(lA, A, m0, 0, t0 + 2);
        BAR(); LGKM0(); MMA_Q(0, 0); BAR();
        // phase 6
        LOAD_B(1, 1);
        if (more) STAGE_HALF(lA, A, m0, 1, t0 + 2);
        BAR(); LGKM0(); MMA_Q(0, 1); BAR();
        // phase 7
        LOAD_A(1, 1);
        if (more) STAGE_HALF(lB, B, n0, 0, t0 + 3);
        BAR(); LGKM0(); MMA_Q(1, 1); BAR();
        // phase 8: confirm tile 2i+2 after MFMA
        if (more) STAGE_HALF(lB, B, n0, 1, t0 + 3);
        BAR(); LGKM0(); MMA_Q(1, 0);
        if (more) VMC4();
        BAR();
    }

    // ---- epilogue; C/D layout: col = lane&15, row = (lane>>4)*4 + r
    const int type = (bx >= 6) ? 2 : (bx >= 3 ? 1 : 0);
    const int nl0 = n0 - type * 768;
    const int r0 = wm + (lane >> 4) * 4;
    const int c0 = wn + (lane & 15);
    if (type < 2) {
        short* dst = (type == 0) ? Q : Kb;
        const int par = lane & 1;
        #pragma unroll
        for (int tmi = 0; tmi < 8; ++tmi)
            #pragma unroll
            for (int tni = 0; tni < 4; ++tni) {
                int col = nl0 + c0 + tni * 16;
                const float2* rtc = rt + (col >> 1);
                #pragma unroll
                for (int r = 0; r < 4; ++r) {
                    int row = m0 + r0 + tmi * 16 + r;
                    float val = acc[tmi][tni][r];
                    float pv = __shfl_xor(val, 1);
                    float2 cs = rtc[(row & 255) * 384];
                    float re = par ? pv : val;
                    float im = par ? val : pv;
                    float o = par ? (re * cs.y + im * cs.x)
                                  : (re * cs.x - im * cs.y);
                    dst[(long)row * 768 + col] = f2bf(o);
                }
            }
    } else {
        #pragma unroll
        for (int tmi = 0; tmi < 8; ++tmi)
            #pragma unroll
            for (int tni = 0; tni < 4; ++tni) {
                int col = nl0 + c0 + tni * 16;
                #pragma unroll
                for (int r = 0; r < 4; ++r) {
                    int row = m0 + r0 + tmi * 16 + r;
                    Vt[((long)(row >> 8) * 768 + col) * 256 + (row & 255)] =
                        f2bf(acc[tmi][tni][r]);
                }
            }
    }
#undef STAGE_HALF
#undef LOAD_A
#undef LOAD_B
#undef MMA_Q
#undef BAR
#undef LGKM0
#undef VMC4
#undef VMC0
}

// ---------------------------------------------------------------------------
// Fused attention tail v5: register-direct operands with a 4-deep prefetch
// ring, __launch_bounds__(256,2) so the allocator has 256 VGPR (v4's (256,3)
// capped at ~168 -> likely spill: acc64+frags64+softmax ~190 at NC=4; v4 ran
// SLOWER than LDS variants, the spill signature). 4-slot ring doubles
// outstanding loads/wave to ~32x16B: latency coverage ~3.5 TB/s vs L3-hit
// latency (per-XCD working set 19MB >> 4MB L2). All ring indices are
// compile-time (unrolled phi loop). Math/accumulation order verbatim from v4
// -> bitwise-identical output. Grid 512 = (XCD, batch, q-quarter).
// LDS 34 KB: P (32K, rotation-swizzled) + f32 softmax scratch (2K).
#define LBAR() do { asm volatile("s_waitcnt lgkmcnt(0)" ::: "memory");         \
                    __builtin_amdgcn_s_barrier(); } while (0)

template <int NC>
__device__ __forceinline__ void attn_core(
    int bz, int qh, const short* __restrict__ qb, const short* __restrict__ kb,
    const short* __restrict__ vt, float* __restrict__ out, float scale,
    short* smem, int w, int lane) {
    const int fr = lane & 15, kq = lane >> 4;
    const int wNC = w * NC;
    const short* Aq = qb + ((long)bz * 256 + qh * 64) * 768;
    const short* Bk = kb + (long)bz * 196608;
    const short* Vv = vt + (long)bz * 196608;   // [768 d][256 t]

    f32x4 acc[4][NC];
    #pragma unroll
    for (int m = 0; m < 4; ++m)
        #pragma unroll
        for (int n = 0; n < NC; ++n) acc[m][n] = (f32x4){0.f, 0.f, 0.f, 0.f};

    short8 aR[4][4];    // [ring slot][m-tile]
    short8 bR[4][NC];   // [ring slot][n-tile]

#define LDQ(sl, ks) do {                                                       \
    _Pragma("unroll")                                                          \
    for (int _m = 0; _m < 4; ++_m)                                             \
        aR[sl][_m] = *(const short8*)(Aq + (long)(_m * 16 + fr) * 768          \
                                      + (ks) * 32 + kq * 8);                   \
    _Pragma("unroll")                                                          \
    for (int _n = 0; _n < NC; ++_n)                                            \
        bR[sl][_n] = *(const short8*)(Bk + (long)((wNC + _n) * 16 + fr) * 768  \
                                      + (ks) * 32 + kq * 8);                   \
} while (0)
#define MMQ(sl) do {                                                           \
    _Pragma("unroll")                                                          \
    for (int _m = 0; _m < 4; ++_m)                                             \
        _Pragma("unroll")                                                      \
        for (int _n = 0; _n < NC; ++_n)                                        \
            acc[_m][_n] = __builtin_amdgcn_mfma_f32_16x16x32_bf16(             \
                aR[sl][_m], bR[sl][_n], acc[_m][_n], 0, 0, 0);                 \
} while (0)

    // ---- phase 1: QK^T, barrier-free, 4-slice ring --------------------
    LDQ(0, 0); LDQ(1, 1); LDQ(2, 2); LDQ(3, 3);
    #pragma unroll 1
    for (int i = 0; i < 6; ++i) {
        const int base = i * 4;
        const bool more = (i < 5);
        #pragma unroll
        for (int ph = 0; ph < 4; ++ph) {
            MMQ(ph);
            if (more) LDQ(ph, base + 4 + ph);
        }
    }

    // ---- phase 2: exact causal softmax (rows 0..63 local) -------------
    const int r0 = kq * 4;
    float* redm = (float*)(smem + 16384);   // [64][4]
    float* reds = redm + 256;               // [64][4]

    float M[16];
    #pragma unroll
    for (int tmi = 0; tmi < 4; ++tmi)
        #pragma unroll
        for (int r = 0; r < 4; ++r) {
            int rowL = tmi * 16 + r0 + r;
            int tloc = qh * 64 + rowL;
            float m = -1e30f;
            #pragma unroll
            for (int tni = 0; tni < NC; ++tni) {
                int col = (wNC + tni) * 16 + fr;
                float v = (col <= tloc) ? acc[tmi][tni][r] * scale : -1e30f;
                acc[tmi][tni][r] = v;
                m = fmaxf(m, v);
            }
            m = fmaxf(m, __shfl_xor(m, 1));
            m = fmaxf(m, __shfl_xor(m, 2));
            m = fmaxf(m, __shfl_xor(m, 4));
            m = fmaxf(m, __shfl_xor(m, 8));
            M[tmi * 4 + r] = m;
        }
    if (fr == 0) {
        #pragma unroll
        for (int tmi = 0; tmi < 4; ++tmi)
            #pragma unroll
            for (int r = 0; r < 4; ++r)
                redm[(tmi * 16 + r0 + r) * 4 + w] = M[tmi * 4 + r];
    }
    LBAR();
    #pragma unroll
    for (int tmi = 0; tmi < 4; ++tmi)
        #pragma unroll
        for (int r = 0; r < 4; ++r) {
            f32x4 v = *(const f32x4*)(redm + (tmi * 16 + r0 + r) * 4);
            M[tmi * 4 + r] = fmaxf(fmaxf(v.x, v.y), fmaxf(v.z, v.w));
        }
    float Sm[16];
    #pragma unroll
    for (int tmi = 0; tmi < 4; ++tmi)
        #pragma unroll
        for (int r = 0; r < 4; ++r) {
            float mm = M[tmi * 4 + r];
            float s = 0.f;
            #pragma unroll
            for (int tni = 0; tni < NC; ++tni) {
                float e = __expf(acc[tmi][tni][r] - mm);
                acc[tmi][tni][r] = e;
                s += e;
            }
            s += __shfl_xor(s, 1);
            s += __shfl_xor(s, 2);
            s += __shfl_xor(s, 4);
            s += __shfl_xor(s, 8);
            Sm[tmi * 4 + r] = s;
        }
    if (fr == 0) {
        #pragma unroll
        for (int tmi = 0; tmi < 4; ++tmi)
            #pragma unroll
            for (int r = 0; r < 4; ++r)
                reds[(tmi * 16 + r0 + r) * 4 + w] = Sm[tmi * 4 + r];
    }
    LBAR();

    // V ring prologue rides under normalize + P-write + barrier
    short8 vR[4][2];    // [ring slot][n-tile]
#define LDV(sl, s) do {                                                        \
    int _dc = (s) / (2 * NC), _ts = (s) - _dc * 2 * NC;                        \
    _Pragma("unroll")                                                          \
    for (int _tn = 0; _tn < 2; ++_tn)                                          \
        vR[sl][_tn] = *(const short8*)(Vv +                                    \
            (long)(_dc * 128 + w * 32 + _tn * 16 + fr) * 256                   \
            + _ts * 32 + kq * 8);                                              \
} while (0)
    LDV(0, 0); LDV(1, 1); LDV(2, 2); LDV(3, 3);

    // normalize + write P into LDS (bf16, rotation-swizzled fragment layout)
    // wave w owns col-tiles ct = wNC+tni: chunk = ct>>2, in-chunk pos = ct&3
    #pragma unroll
    for (int tmi = 0; tmi < 4; ++tmi)
        #pragma unroll
        for (int r = 0; r < 4; ++r) {
            int rowL = tmi * 16 + r0 + r;
            f32x4 sv = *(const f32x4*)(reds + rowL * 4);
            float inv = 1.0f / (sv.x + sv.y + sv.z + sv.w);
            #pragma unroll
            for (int tni = 0; tni < NC; ++tni) {
                int ct = wNC + tni;
                int l = (ct & 3) * 2 + (fr >> 3);      // logical 8-short slot
                smem[(ct >> 2) * 4096 + rowL * 64 +
                     ((l + rowL) & 7) * 8 + (fr & 7)] =
                    f2bf(acc[tmi][tni][r] * inv);
            }
        }
    LBAR();   // P visible (lgkm-only: V prefetch keeps flying)

    // ---- phase 3: PV, barrier-free, 4-slice V ring --------------------
    // slice s: dc = s/(2NC), ts = s%(2NC); P chunk kc = ts>>1, half cc = ts&1
    f32x4 a2[4][2] = {};
    const long rowB = (long)bz * 256 + (long)qh * 64;
#define MMP(sl, s) do {                                                        \
    int _dc2 = (s) / (2 * NC), _ts2 = (s) - _dc2 * 2 * NC;                     \
    int _kc = _ts2 >> 1, _cc = _ts2 & 1;                                       \
    const short* _p = smem + _kc * 4096;                                       \
    const int _sp = ((_cc * 4 + kq + fr) & 7) * 8;                             \
    _Pragma("unroll")                                                          \
    for (int _m = 0; _m < 4; ++_m) {                                           \
        short8 _ap = *(const short8*)(_p + (_m * 16 + fr) * 64 + _sp);         \
        _Pragma("unroll")                                                      \
        for (int _tn = 0; _tn < 2; ++_tn)                                      \
            a2[_m][_tn] = __builtin_amdgcn_mfma_f32_16x16x32_bf16(             \
                _ap, vR[sl][_tn], a2[_m][_tn], 0, 0, 0);                       \
    }                                                                          \
} while (0)
#define STO(dcv) do {                                                          \
    _Pragma("unroll")                                                          \
    for (int _m = 0; _m < 4; ++_m)                                             \
        _Pragma("unroll")                                                      \
        for (int _tn = 0; _tn < 2; ++_tn)                                      \
            _Pragma("unroll")                                                  \
            for (int _r = 0; _r < 4; ++_r) {                                   \
                long _row = rowB + _m * 16 + kq * 4 + _r;                      \
                int _col = (dcv) * 128 + w * 32 + _tn * 16 + fr;               \
                out[_row * 768 + _col] = a2[_m][_tn][_r];                      \
            }                                                                  \
    _Pragma("unroll")                                                          \
    for (int _m = 0; _m < 4; ++_m)                                             \
        _Pragma("unroll")                                                      \
        for (int _tn = 0; _tn < 2; ++_tn)                                      \
            a2[_m][_tn] = (f32x4){0.f, 0.f, 0.f, 0.f};                         \
} while (0)

    const int SL = 12 * NC;             // total slices (divisible by 4)
    #pragma unroll 1
    for (int sb = 0; sb < SL; sb += 4) {
        #pragma unroll
        for (int ph = 0; ph < 4; ++ph) {
            const int s = sb + ph;
            MMP(ph, s);
            if (s + 4 < SL) LDV(ph, s + 4);
            if (((s + 1) % (2 * NC)) == 0) STO(s / (2 * NC));
        }
    }
#undef LDQ
#undef MMQ
#undef LDV
#undef MMP
#undef STO
}

__global__ __launch_bounds__(256, 2)
void attn5(const short* __restrict__ Qm, const short* __restrict__ Km,
           const short* __restrict__ Vm, float* __restrict__ out,
           float scale) {
    __shared__ short smem[17408];       // 34 KB: P(32K) + f32 scratch(2K)
    int p = blockIdx.x;
    int c = p & 7, j = p >> 3;          // j in [0,64)
    int b = j >> 2, q0 = j & 3;
    int qh = (b & 8) ? 3 - q0 : q0;     // heavy/light pairing across rounds
    int bz = c * 16 + b;
    int w = threadIdx.x >> 6, lane = threadIdx.x & 63;
    switch (qh) {
        case 0:  attn_core<1>(bz, qh, Qm, Km, Vm, out, scale, smem, w, lane); break;
        case 1:  attn_core<2>(bz, qh, Qm, Km, Vm, out, scale, smem, w, lane); break;
        case 2:  attn_core<3>(bz, qh, Qm, Km, Vm, out, scale, smem, w, lane); break;
        default: attn_core<4>(bz, qh, Qm, Km, Vm, out, scale, smem, w, lane); break;
    }
}
#undef LBAR

// ---------------------------------------------------------------------------
extern "C" void kernel_launch(void* const* d_in, const int* in_sizes, int n_in,
                              void* d_out, int out_size, void* d_ws, size_t ws_size,
                              hipStream_t stream) {
    const float* x  = (const float*)d_in[0];
    const float* Wq = (const float*)d_in[1];
    const float* Wk = (const float*)d_in[2];
    const float* Wv = (const float*)d_in[3];

    char* ws = (char*)d_ws;
    short*  xb = (short*)(ws);                   // 48 MB   x bf16
    short*  wt = (short*)(ws + 50331648);        // 3.375MB Wqkv^T bf16 [2304,768]
    short*  qb = (short*)(ws + 53870592);        // 48 MB   q bf16 (roped)
    short*  kb = (short*)(ws + 104202240);       // 48 MB   k bf16 (roped)
    short*  vt = (short*)(ws + 154533888);       // 48 MB   v^T bf16 [128][768][256]
    float2* rt = (float2*)(ws + 255197184);      // 768 KB  rope table

    cvt_x<<<24576, 256, 0, stream>>>(x, xb);
    dim3 gw(24, 24);
    cvt_wt<<<gw, 256, 0, stream>>>(Wq, wt);
    cvt_wt<<<gw, 256, 0, stream>>>(Wk, wt + 589824);
    cvt_wt<<<gw, 256, 0, stream>>>(Wv, wt + 1179648);
    rope_tab<<<384, 256, 0, stream>>>(rt);

    // Fused QKV: [32768,768] x [2304,768]^T, 256^2 8-phase, RoPE/v-T epilogue
    qkv256<<<1152, 512, 0, stream>>>(xb, wt, qb, kb, vt, rt);

    // Fused attention tail v5: 4-deep reg ring, 256-VGPR budget, no spill
    attn5<<<512, 256, 0, stream>>>(qb, kb, vt, (float*)d_out, 0.0360843918f);
}

// Round 8
// 385.357 us; speedup vs baseline: 1.0682x; 1.0682x over previous
//
#include <hip/hip_runtime.h>
#include <hip/hip_bf16.h>
#include <stdint.h>

// B=128, T=256, C=768, D=768. M_total = 32768.

typedef __attribute__((ext_vector_type(8))) short short8;   // 8 x bf16 (4 VGPRs)
typedef __attribute__((ext_vector_type(4))) short short4v;  // 4 x bf16 (8B)
typedef __attribute__((ext_vector_type(4))) float f32x4;

__device__ __forceinline__ short f2bf(float f) {
    uint32_t u = __float_as_uint(f);
    u += 0x7fffu + ((u >> 16) & 1u);   // RNE
    return (short)(u >> 16);
}

// ---------------------------------------------------------------------------
// prep: merged cvt_x (24576 blocks) + 3x cvt_wt (3x576) + rope_tab (384).
// Grid 26688 x 256. Saves 4 launch boundaries vs separate kernels.
__global__ __launch_bounds__(256)
void prep(const float* __restrict__ x, const float* __restrict__ Wq,
          const float* __restrict__ Wk, const float* __restrict__ Wv,
          short* __restrict__ xb, short* __restrict__ wt,
          float2* __restrict__ rt) {
    __shared__ float tile[32][33];
    const int bid = blockIdx.x;
    const int tid = threadIdx.x;
    if (bid < 24576) {
        long i = ((long)bid * 256 + tid) * 4;
        f32x4 v = *(const f32x4*)(x + i);
        short4v o;
        o.x = f2bf(v.x); o.y = f2bf(v.y); o.z = f2bf(v.z); o.w = f2bf(v.w);
        *(short4v*)(xb + i) = o;
    } else if (bid < 26304) {
        int r = bid - 24576;
        int wsel = r / 576;
        int t2 = r - wsel * 576;
        const float* W = (wsel == 0) ? Wq : (wsel == 1 ? Wk : Wv);
        short* Wt = wt + wsel * 589824;
        int d0 = (t2 % 24) * 32, c0 = (t2 / 24) * 32;
        int tr = tid >> 5, tc = tid & 31;
        #pragma unroll
        for (int i = 0; i < 32; i += 8)
            tile[tr + i][tc] = W[(long)(c0 + tr + i) * 768 + d0 + tc];
        __syncthreads();
        #pragma unroll
        for (int i = 0; i < 32; i += 8)
            Wt[(long)(d0 + tr + i) * 768 + c0 + tc] = f2bf(tile[tc][tr + i]);
    } else {
        int i = (bid - 26304) * 256 + tid;   // [0, 98304)
        int t = i / 384, j = i - t * 384;
        const float CE = -0.034603417655f;   // -2*log2(10000)/768
        float th = exp2f((float)j * CE);
        float s, c;
        sincosf((float)t * th, &s, &c);
        rt[i] = make_float2(c, s);
    }
}

// ---------------------------------------------------------------------------
// Fused QKV GEMM: 256x256 tile, BK=64, 8 waves (2Mx4N), 8-phase schedule.
// DEEPENED PIPELINE (this round): tile t+2's B staged at ph3, A at ph4
// (legal: buf-B free after ph2, buf-A free after ph3 -- every reader's
// ds_read retires before that phase's closing barrier). 8 loads = 2 full
// tiles in flight; vmcnt(8) at ph4/ph8 drains the tile consumed NEXT while
// the just-staged tile rides across 4 phases + 2 barriers of cover.
// C = A[32768x768] x B[2304x768]^T; epilogue: RoPE (q,k), transpose (v).
__global__ __launch_bounds__(512, 2)
void qkv256(const short* __restrict__ A, const short* __restrict__ B,
            short* __restrict__ Q, short* __restrict__ Kb,
            short* __restrict__ Vt, const float2* __restrict__ rt) {
    // grid 1152 flat = 8 XCDs x 16 M-stripes x 9 N-blocks (bijective)
    int p = blockIdx.x;
    int c = p & 7, j = p >> 3;          // j in [0,144)
    int st = j / 9;
    int bx = j - st * 9;                // [0,9)
    int by = c * 16 + st;               // [0,128)
    const int m0 = by * 256, n0 = bx * 256;

    __shared__ short lA[2][256 * 64];   // 64 KB
    __shared__ short lB[2][256 * 64];   // 64 KB

    const int tid = threadIdx.x;
    const int w = tid >> 6, lane = tid & 63;
    const int wm = (w >> 2) * 128;      // 2 M-waves
    const int wn = (w & 3) * 64;        // 4 N-waves
    const int lr8 = lane >> 3;
    const int scol = (((lane & 7) - lr8) & 7) * 8;  // rotation swizzle (stage)
    const int fr = lane & 15, kq = lane >> 4;

    f32x4 acc[8][4] = {};
    short8 af[4][2];
    short8 bq[4][2];

#define STAGE_HALF(lX, gX, r0g, h, t) do {                                     \
    int _buf = (t) & 1;                                                        \
    _Pragma("unroll")                                                          \
    for (int _i = 0; _i < 2; ++_i) {                                           \
        int _rl = (h) * 128 + (w * 2 + _i) * 8;                                \
        const short* _g = (gX) + (long)((r0g) + _rl + lr8) * 768               \
                               + (t) * 64 + scol;                              \
        __builtin_amdgcn_global_load_lds(                                      \
            (const __attribute__((address_space(1))) void*)_g,                 \
            (__attribute__((address_space(3))) void*)(&lX[_buf][_rl * 64]),    \
            16, 0, 0);                                                         \
    }                                                                          \
} while (0)

#define LOAD_A(mh, buf) do {                                                   \
    _Pragma("unroll")                                                          \
    for (int _t = 0; _t < 4; ++_t)                                             \
        _Pragma("unroll")                                                      \
        for (int _k = 0; _k < 2; ++_k)                                         \
            af[_t][_k] = *(const short8*)(&lA[buf][                            \
                (wm + (mh) * 64 + _t * 16 + fr) * 64 +                         \
                ((_k * 4 + kq + fr) & 7) * 8]);                                \
} while (0)

#define LOAD_B(nh, buf) do {                                                   \
    _Pragma("unroll")                                                          \
    for (int _t = 0; _t < 2; ++_t)                                             \
        _Pragma("unroll")                                                      \
        for (int _k = 0; _k < 2; ++_k)                                         \
            bq[(nh) * 2 + _t][_k] = *(const short8*)(&lB[buf][                 \
                (wn + (nh) * 32 + _t * 16 + fr) * 64 +                         \
                ((_k * 4 + kq + fr) & 7) * 8]);                                \
} while (0)

#define MMA_Q(mh, nh) do {                                                     \
    __builtin_amdgcn_s_setprio(1);                                             \
    _Pragma("unroll")                                                          \
    for (int _t = 0; _t < 4; ++_t)                                             \
        _Pragma("unroll")                                                      \
        for (int _n = 0; _n < 2; ++_n)                                         \
            _Pragma("unroll")                                                  \
            for (int _k = 0; _k < 2; ++_k)                                     \
                acc[(mh) * 4 + _t][(nh) * 2 + _n] =                            \
                    __builtin_amdgcn_mfma_f32_16x16x32_bf16(                   \
                        af[_t][_k], bq[(nh) * 2 + _n][_k],                     \
                        acc[(mh) * 4 + _t][(nh) * 2 + _n], 0, 0, 0);           \
    __builtin_amdgcn_s_setprio(0);                                             \
} while (0)

#define BAR() __builtin_amdgcn_s_barrier()
#define LGKM0() asm volatile("s_waitcnt lgkmcnt(0)" ::: "memory")
#define VMC8() asm volatile("s_waitcnt vmcnt(8)" ::: "memory")
#define VMC0() asm volatile("s_waitcnt vmcnt(0)" ::: "memory")

    // prologue: T0 {B0,B1,A0,A1}, T1 {B0,B1,A0,A1}; drain T0 (T1 rides)
    STAGE_HALF(lB, B, n0, 0, 0);
    STAGE_HALF(lB, B, n0, 1, 0);
    STAGE_HALF(lA, A, m0, 0, 0);
    STAGE_HALF(lA, A, m0, 1, 0);
    STAGE_HALF(lB, B, n0, 0, 1);
    STAGE_HALF(lB, B, n0, 1, 1);
    STAGE_HALF(lA, A, m0, 0, 1);
    STAGE_HALF(lA, A, m0, 1, 1);
    VMC8();
    BAR();

    #pragma unroll 1
    for (int i = 0; i < 6; ++i) {
        const int t0 = 2 * i;
        const bool more = (i < 5);
        // phase 1
        LOAD_A(0, 0); LOAD_B(0, 0);
        BAR(); LGKM0(); MMA_Q(0, 0); BAR();
        // phase 2
        LOAD_B(1, 0);
        BAR(); LGKM0(); MMA_Q(0, 1); BAR();
        // phase 3: buf0-B free after ph2 -> stage B(t+2) now
        LOAD_A(1, 0);
        if (more) { STAGE_HALF(lB, B, n0, 0, t0 + 2);
                    STAGE_HALF(lB, B, n0, 1, t0 + 2); }
        BAR(); LGKM0(); MMA_Q(1, 1); BAR();
        // phase 4: buf0-A free after ph3 -> stage A(t+2); drain tile t+1
        if (more) { STAGE_HALF(lA, A, m0, 0, t0 + 2);
                    STAGE_HALF(lA, A, m0, 1, t0 + 2); }
        BAR(); LGKM0(); MMA_Q(1, 0);
        if (more) { VMC8(); } else { VMC0(); }
        BAR();
        // phase 5
        LOAD_A(0, 1); LOAD_B(0, 1);
        BAR(); LGKM0(); MMA_Q(0, 0); BAR();
        // phase 6
        LOAD_B(1, 1);
        BAR(); LGKM0(); MMA_Q(0, 1); BAR();
        // phase 7: buf1-B free after ph6 -> stage B(t+3)
        LOAD_A(1, 1);
        if (more) { STAGE_HALF(lB, B, n0, 0, t0 + 3);
                    STAGE_HALF(lB, B, n0, 1, t0 + 3); }
        BAR(); LGKM0(); MMA_Q(1, 1); BAR();
        // phase 8: buf1-A free after ph7 -> stage A(t+3); drain tile t+2
        if (more) { STAGE_HALF(lA, A, m0, 0, t0 + 3);
                    STAGE_HALF(lA, A, m0, 1, t0 + 3); }
        BAR(); LGKM0(); MMA_Q(1, 0);
        if (more) VMC8();
        BAR();
    }

    // ---- epilogue; C/D layout: col = lane&15, row = (lane>>4)*4 + r
    const int type = (bx >= 6) ? 2 : (bx >= 3 ? 1 : 0);
    const int nl0 = n0 - type * 768;
    const int r0 = wm + (lane >> 4) * 4;
    const int c0 = wn + (lane & 15);
    if (type < 2) {
        short* dst = (type == 0) ? Q : Kb;
        const int par = lane & 1;
        #pragma unroll
        for (int tmi = 0; tmi < 8; ++tmi)
            #pragma unroll
            for (int tni = 0; tni < 4; ++tni) {
                int col = nl0 + c0 + tni * 16;
                const float2* rtc = rt + (col >> 1);
                #pragma unroll
                for (int r = 0; r < 4; ++r) {
                    int row = m0 + r0 + tmi * 16 + r;
                    float val = acc[tmi][tni][r];
                    float pv = __shfl_xor(val, 1);
                    float2 cs = rtc[(row & 255) * 384];
                    float re = par ? pv : val;
                    float im = par ? val : pv;
                    float o = par ? (re * cs.y + im * cs.x)
                                  : (re * cs.x - im * cs.y);
                    dst[(long)row * 768 + col] = f2bf(o);
                }
            }
    } else {
        #pragma unroll
        for (int tmi = 0; tmi < 8; ++tmi)
            #pragma unroll
            for (int tni = 0; tni < 4; ++tni) {
                int col = nl0 + c0 + tni * 16;
                #pragma unroll
                for (int r = 0; r < 4; ++r) {
                    int row = m0 + r0 + tmi * 16 + r;
                    Vt[((long)(row >> 8) * 768 + col) * 256 + (row & 255)] =
                        f2bf(acc[tmi][tni][r]);
                }
            }
    }
#undef STAGE_HALF
#undef LOAD_A
#undef LOAD_B
#undef MMA_Q
#undef BAR
#undef LGKM0
#undef VMC8
#undef VMC0
}

// ---------------------------------------------------------------------------
// Fully fused attention tail (r3 kernel, best-measured variant -- verbatim).
// One kernel, grid 256 (1 block/CU, XCD-paired), 512 threads = 8 waves.
// Phase 1 (QK): 128 q-rows x 256 k-cols, K=768, double-buffered staging.
// Phase 2: exact softmax (full row in registers), P -> LDS bf16 in the
//   rotation-swizzled fragment layout (phys slot = (t'/8 + row) & 7).
// Phase 3 (PV): out[128][768] in 6 d-chunks of 128; A = P from LDS,
//   B = vt tiles double-buffered; causal limit kcN = mh ? 4 : 2.
// LDS map (shorts): [0,16384) lA dbuf | [16384,49152) lB dbuf
//   P chunks [0,32768) alias QK bufs after QK done
//   [49152,65536) lV dbuf | [65536,67584) f32 reduction scratch. 132 KB.
__global__ __launch_bounds__(512)
void attn_fused(const short* __restrict__ Qm, const short* __restrict__ Km,
                const short* __restrict__ Vm, float* __restrict__ out,
                float scale) {
    int p = blockIdx.x;
    int c = p & 7, j = p >> 3;          // j in [0,32)
    int bz = c * 16 + (j >> 1);
    int mh = j & 1;
    const short* Ab = Qm + (long)bz * 196608 + (long)mh * 98304;
    const short* Bb = Km + (long)bz * 196608;
    const short* Vb = Vm + (long)bz * 196608;   // vt[batch][768 d][256 t]

    __shared__ short smem[67584];

    const int tid = threadIdx.x;
    const int w = tid >> 6, lane = tid & 63;
    const int wm = (w >> 2) * 64;       // 2 m-groups of 64 q-rows
    const int wn = (w & 3) * 64;        // 4 n-groups of 64 t-cols (QK)
    const int lr8 = lane >> 3;
    const int scol = (((lane & 7) - lr8) & 7) * 8;
    const int fr = lane & 15, kq = lane >> 4;
    const int cb = fr;

    f32x4 acc[4][4] = {};

#define GLL(g, l) __builtin_amdgcn_global_load_lds(                            \
        (const __attribute__((address_space(1))) void*)(g),                    \
        (__attribute__((address_space(3))) void*)(l), 16, 0, 0)

#define STAGE_QK(t) do { int _b = (t) & 1;                                     \
    _Pragma("unroll")                                                          \
    for (int _i = 0; _i < 2; ++_i) { int _s = _i * 8 + w;                      \
        GLL(Ab + (long)(_s * 8 + lr8) * 768 + (t) * 64 + scol,                 \
            smem + _b * 8192 + _s * 512); }                                    \
    _Pragma("unroll")                                                          \
    for (int _i = 0; _i < 4; ++_i) { int _s = _i * 8 + w;                      \
        GLL(Bb + (long)(_s * 8 + lr8) * 768 + (t) * 64 + scol,                 \
            smem + 16384 + _b * 16384 + _s * 512); } } while (0)

#define STAGE_V(dc, kc, b) do {                                                \
    _Pragma("unroll")                                                          \
    for (int _i = 0; _i < 2; ++_i) { int _s = _i * 8 + w;                      \
        GLL(Vb + (long)((dc) * 128 + _s * 8 + lr8) * 256 + (kc) * 64 + scol,   \
            smem + 49152 + (b) * 8192 + _s * 512); } } while (0)

    // ---- phase 1: QK, double-buffered ---------------------------------
    STAGE_QK(0);
    __syncthreads();
    #pragma unroll 1
    for (int t = 0; t < 12; ++t) {
        if (t < 11) STAGE_QK(t + 1);
        const short* la = smem + (t & 1) * 8192;
        const short* lb = smem + 16384 + (t & 1) * 16384;
        #pragma unroll
        for (int cc = 0; cc < 2; ++cc) {
            const int sphys = ((cc * 4 + kq + fr) & 7) * 8;
            short8 afr[4], bfr[4];
            #pragma unroll
            for (int tmi = 0; tmi < 4; ++tmi)
                afr[tmi] = *(const short8*)(la + (wm + fr + tmi * 16) * 64 + sphys);
            #pragma unroll
            for (int tni = 0; tni < 4; ++tni)
                bfr[tni] = *(const short8*)(lb + (wn + fr + tni * 16) * 64 + sphys);
            #pragma unroll
            for (int tmi = 0; tmi < 4; ++tmi)
                #pragma unroll
                for (int tni = 0; tni < 4; ++tni)
                    acc[tmi][tni] = __builtin_amdgcn_mfma_f32_16x16x32_bf16(
                        afr[tmi], bfr[tni], acc[tmi][tni], 0, 0, 0);
        }
        __syncthreads();
    }

    // V tile (0,0) fetch rides under the softmax
    STAGE_V(0, 0, 0);

    // ---- phase 2: exact causal softmax --------------------------------
    const int r0 = kq * 4;
    const int nw = w & 3;
    float* redm = (float*)(smem + 65536);
    float* reds = redm + 512;

    float M[16];
    #pragma unroll
    for (int tmi = 0; tmi < 4; ++tmi)
        #pragma unroll
        for (int r = 0; r < 4; ++r) {
            int rowL = wm + tmi * 16 + r0 + r;
            int tloc = mh * 128 + rowL;
            float m = -1e30f;
            #pragma unroll
            for (int tni = 0; tni < 4; ++tni) {
                int col = wn + cb + tni * 16;
                float v = (col <= tloc) ? acc[tmi][tni][r] * scale : -1e30f;
                acc[tmi][tni][r] = v;
                m = fmaxf(m, v);
            }
            m = fmaxf(m, __shfl_xor(m, 1));
            m = fmaxf(m, __shfl_xor(m, 2));
            m = fmaxf(m, __shfl_xor(m, 4));
            m = fmaxf(m, __shfl_xor(m, 8));
            M[tmi * 4 + r] = m;
        }
    if (cb == 0) {
        #pragma unroll
        for (int tmi = 0; tmi < 4; ++tmi)
            #pragma unroll
            for (int r = 0; r < 4; ++r)
                redm[(wm + tmi * 16 + r0 + r) * 4 + nw] = M[tmi * 4 + r];
    }
    __syncthreads();
    #pragma unroll
    for (int tmi = 0; tmi < 4; ++tmi)
        #pragma unroll
        for (int r = 0; r < 4; ++r) {
            f32x4 v = *(const f32x4*)(redm + (wm + tmi * 16 + r0 + r) * 4);
            M[tmi * 4 + r] = fmaxf(fmaxf(v.x, v.y), fmaxf(v.z, v.w));
        }
    float Sm[16];
    #pragma unroll
    for (int tmi = 0; tmi < 4; ++tmi)
        #pragma unroll
        for (int r = 0; r < 4; ++r) {
            float mm = M[tmi * 4 + r];
            float s = 0.f;
            #pragma unroll
            for (int tni = 0; tni < 4; ++tni) {
                float e = __expf(acc[tmi][tni][r] - mm);
                acc[tmi][tni][r] = e;
                s += e;
            }
            s += __shfl_xor(s, 1);
            s += __shfl_xor(s, 2);
            s += __shfl_xor(s, 4);
            s += __shfl_xor(s, 8);
            Sm[tmi * 4 + r] = s;
        }
    if (cb == 0) {
        #pragma unroll
        for (int tmi = 0; tmi < 4; ++tmi)
            #pragma unroll
            for (int r = 0; r < 4; ++r)
                reds[(wm + tmi * 16 + r0 + r) * 4 + nw] = Sm[tmi * 4 + r];
    }
    __syncthreads();

    // normalize + write P into LDS (bf16, rotation-swizzled fragment layout)
    short* Pch = smem + (w & 3) * 8192;
    #pragma unroll
    for (int tmi = 0; tmi < 4; ++tmi)
        #pragma unroll
        for (int r = 0; r < 4; ++r) {
            int rowL = wm + tmi * 16 + r0 + r;
            f32x4 sv = *(const f32x4*)(reds + rowL * 4);
            float inv = 1.0f / (sv.x + sv.y + sv.z + sv.w);
            #pragma unroll
            for (int tni = 0; tni < 4; ++tni) {
                int l = (cb >> 3) + tni * 2;            // logical 8-short slot
                Pch[rowL * 64 + ((l + rowL) & 7) * 8 + (cb & 7)] =
                    f2bf(acc[tmi][tni][r] * inv);
            }
        }
    __syncthreads();   // P visible; V tile (0,0) complete (vmcnt drained)

    // ---- phase 3: PV, double-buffered V -------------------------------
    const int kcN = mh ? 4 : 2;          // causal t-extent: chunks of 64
    const int wn2 = (w & 3) * 32;        // 4 n-groups of 32 d-cols
    const long rowB = (long)bz * 256 + (long)mh * 128;
    int vb = 0;
    #pragma unroll 1
    for (int dc = 0; dc < 6; ++dc) {
        f32x4 a2[4][2] = {};
        #pragma unroll 1
        for (int kc = 0; kc < kcN; ++kc) {
            int ndc = dc, nkc = kc + 1;
            if (nkc == kcN) { ndc = dc + 1; nkc = 0; }
            if (ndc < 6) STAGE_V(ndc, nkc, vb ^ 1);
            const short* pch = smem + kc * 8192;
            const short* lv = smem + 49152 + vb * 8192;
            #pragma unroll
            for (int cc = 0; cc < 2; ++cc) {
                const int sp = ((cc * 4 + kq + fr) & 7) * 8;
                short8 ap[4], bv[2];
                #pragma unroll
                for (int tmi = 0; tmi < 4; ++tmi)
                    ap[tmi] = *(const short8*)(pch + (wm + tmi * 16 + fr) * 64 + sp);
                #pragma unroll
                for (int tn = 0; tn < 2; ++tn)
                    bv[tn] = *(const short8*)(lv + (wn2 + tn * 16 + fr) * 64 + sp);
                #pragma unroll
                for (int tmi = 0; tmi < 4; ++tmi)
                    #pragma unroll
                    for (int tn = 0; tn < 2; ++tn)
                        a2[tmi][tn] = __builtin_amdgcn_mfma_f32_16x16x32_bf16(
                            ap[tmi], bv[tn], a2[tmi][tn], 0, 0, 0);
            }
            __syncthreads();
            vb ^= 1;
        }
        // store out chunk [128 q][128 d], fp32
        #pragma unroll
        for (int tmi = 0; tmi < 4; ++tmi)
            #pragma unroll
            for (int tn = 0; tn < 2; ++tn)
                #pragma unroll
                for (int r = 0; r < 4; ++r) {
                    long row = rowB + wm + tmi * 16 + kq * 4 + r;
                    int col = dc * 128 + wn2 + tn * 16 + cb;
                    out[row * 768 + col] = a2[tmi][tn][r];
                }
    }
#undef GLL
#undef STAGE_QK
#undef STAGE_V
}

// ---------------------------------------------------------------------------
extern "C" void kernel_launch(void* const* d_in, const int* in_sizes, int n_in,
                              void* d_out, int out_size, void* d_ws, size_t ws_size,
                              hipStream_t stream) {
    const float* x  = (const float*)d_in[0];
    const float* Wq = (const float*)d_in[1];
    const float* Wk = (const float*)d_in[2];
    const float* Wv = (const float*)d_in[3];

    char* ws = (char*)d_ws;
    short*  xb = (short*)(ws);                   // 48 MB   x bf16
    short*  wt = (short*)(ws + 50331648);        // 3.375MB Wqkv^T bf16 [2304,768]
    short*  qb = (short*)(ws + 53870592);        // 48 MB   q bf16 (roped)
    short*  kb = (short*)(ws + 104202240);       // 48 MB   k bf16 (roped)
    short*  vt = (short*)(ws + 154533888);       // 48 MB   v^T bf16 [128][768][256]
    float2* rt = (float2*)(ws + 255197184);      // 768 KB  rope table

    // merged converters + rope table
    prep<<<26688, 256, 0, stream>>>(x, Wq, Wk, Wv, xb, wt, rt);

    // Fused QKV: 256^2 8-phase, deepened 2-tile-in-flight prefetch
    qkv256<<<1152, 512, 0, stream>>>(xb, wt, qb, kb, vt, rt);

    // Fused attention tail (r3 best-measured kernel, verbatim)
    attn_fused<<<256, 512, 0, stream>>>(qb, kb, vt, (float*)d_out,
                                        0.0360843918f);
}